// Round 10
// baseline (351.142 us; speedup 1.0000x reference)
//
#include <hip/hip_runtime.h>

typedef short bf16x8 __attribute__((ext_vector_type(8)));
typedef float f32x4 __attribute__((ext_vector_type(4)));
typedef unsigned short u16;

__device__ __forceinline__ u16 f2bf(float f) {
    unsigned u = __builtin_bit_cast(unsigned, f);
    return (u16)((u + 0x7fffu + ((u >> 16) & 1u)) >> 16);   // RNE
}

// Unit map (single persistent kernel, counter-ordered phases):
//   [0,40)      transpose: ApT/AmT[k][o][d] = (Mp +/- Mm)[k][d][o]
//   [40,296)    xpad: bf16 pad/convert of x (256 units)
//   [296,424)   zero d_out (128 units)
//   [424,1448)  build W (1024 units, J-major: unit v -> Jg=v>>4, qb=v&15)
//   [1448,2568) spectral (1120 units, R7 J-major + tail taper)
// Deps: build spins tdone==40; spectral spins p0done==384 once + jdone[J]>=16
// per task. Release: __syncthreads (drains all waves' stores, compiler emits
// vmcnt(0) before s_barrier) + tid0 __threadfence + agent-scope release add.
#define U_XP   40
#define U_ZE   296
#define U_BU   424
#define U_SP   1448
#define U_END  2568

__global__ __launch_bounds__(256, 2)
void k_fused(const float* __restrict__ x, const float* __restrict__ phi,
             const float* __restrict__ Mar,
             const float* __restrict__ Mp, const float* __restrict__ Mm,
             u16* __restrict__ xpad, u16* __restrict__ wg,
             float* __restrict__ ApT, float* __restrict__ AmT,
             float* __restrict__ out, int* __restrict__ ctrl) {
    __shared__ __align__(16) u16 xs[2 * 191 * 64];       // 47.75 KB x window
    __shared__ __align__(16) u16 wsm[2 * 64 * 64];       // 16 KB W pair / merge buf
    __shared__ int sh;

    int* unitc  = ctrl;        // grab counter
    int* tdone  = ctrl + 1;    // transpose units done (40)
    int* p0done = ctrl + 2;    // xpad+zero units done (384)
    int* jdone  = ctrl + 4;    // [64] build units done per J-group (16 each)

    const int tid  = threadIdx.x;
    const int lane = tid & 63, w = tid >> 6;
    const int m15  = lane & 15, q4 = lane >> 4;
    const int par  = w >> 1, batch = w & 1;              // spectral wave role
    const int f0 = tid * 2, f1 = tid * 2 + 1;            // W staging granules
    const int l0 = (((f0 >> 3) * 8) + ((f0 & 7) ^ ((f0 >> 3) & 7))) * 8;
    const int l1 = (((f1 >> 3) * 8) + ((f1 & 7) ^ ((f1 >> 3) & 7))) * 8;

    bool seen_t = false, seen_p0 = false;

    for (;;) {
        __syncthreads();                                 // xs/wsm/sh reuse guard
        if (tid == 0) sh = atomicAdd(unitc, 1);
        __syncthreads();
        const int U = sh;
        if (U >= U_END) break;

        if (U < U_XP) {                                  // ---- transpose ----
            float* tp = (float*)xs;                      // 16.25 KB
            float* tm = tp + 64 * 65;
            const int k = U;
            for (int f = tid; f < 4096; f += 256) {      // f = d*64 + o
                int d = f >> 6, o = f & 63;
                float p = Mp[k * 4096 + f], m = Mm[k * 4096 + f];
                tp[o * 65 + d] = p + m;
                tm[o * 65 + d] = p - m;
            }
            __syncthreads();
            for (int f = tid; f < 4096; f += 256) {      // f = o*64 + d
                int o = f >> 6, d = f & 63;
                ApT[k * 4096 + f] = tp[o * 65 + d];
                AmT[k * 4096 + f] = tm[o * 65 + d];
            }
            __syncthreads();
            if (tid == 0) {
                __threadfence();
                __hip_atomic_fetch_add(tdone, 1, __ATOMIC_RELEASE, __HIP_MEMORY_SCOPE_AGENT);
            }
        } else if (U < U_ZE) {                           // ---- xpad ----
            const int u = U - U_XP;
            #pragma unroll
            for (int i = 0; i < 4; ++i) {
                int gid = (u * 4 + i) * 256 + tid;
                int b = gid >> 17, rem = gid & 131071;
                int r = rem >> 4, c4 = rem & 15;
                u16 o0 = 0, o1 = 0, o2 = 0, o3 = 0;
                if (r >= 4096) {
                    const f32x4 v = *(const f32x4*)(x + ((b << 12) + (r - 4096)) * 64 + c4 * 4);
                    o0 = f2bf(v.x); o1 = f2bf(v.y); o2 = f2bf(v.z); o3 = f2bf(v.w);
                }
                u16* p = xpad + ((b << 13) + r) * 64 + c4 * 4;
                p[0] = o0; p[1] = o1; p[2] = o2; p[3] = o3;
            }
            __syncthreads();
            if (tid == 0) {
                __threadfence();
                __hip_atomic_fetch_add(p0done, 1, __ATOMIC_RELEASE, __HIP_MEMORY_SCOPE_AGENT);
            }
        } else if (U < U_BU) {                           // ---- zero out ----
            float* po = out + (U - U_ZE) * 4096;
            #pragma unroll
            for (int i = 0; i < 4; ++i)
                *(f32x4*)(po + (tid + i * 256) * 4) = (f32x4){0.f, 0.f, 0.f, 0.f};
            __syncthreads();
            if (tid == 0) {
                __threadfence();
                __hip_atomic_fetch_add(p0done, 1, __ATOMIC_RELEASE, __HIP_MEMORY_SCOPE_AGENT);
            }
        } else if (U < U_SP) {                           // ---- build W ----
            if (!seen_t) {
                if (tid == 0)
                    while (__hip_atomic_load(tdone, __ATOMIC_ACQUIRE, __HIP_MEMORY_SCOPE_AGENT) < 40)
                        __builtin_amdgcn_s_sleep(2);
                __syncthreads();
                seen_t = true;
            }
            const int v = U - U_BU;
            const int Jg = v >> 4, qb = v & 15;
            const int s0 = Jg * 64;
            const int q  = qb * 256 + tid;
            const int o  = q >> 6, d = q & 63;

            float ap[40], am[40];
            #pragma unroll
            for (int k = 0; k < 40; ++k) {               // coalesced (q-contiguous)
                ap[k] = ApT[k * 4096 + q];
                am[k] = AmT[k * 4096 + q];
            }
            for (int j = 0; j < 64; j += 2) {
                const float* ph = phi + (s0 + j) * 40;   // wave-uniform -> s_load
                float a0 = 0.f, a1 = 0.f, b0 = 0.f, b1 = 0.f;
                #pragma unroll
                for (int k = 0; k < 40; k += 2) { a0 += ph[k] * ap[k]; a1 += ph[k + 1] * ap[k + 1]; }
                #pragma unroll
                for (int k = 0; k < 40; k += 2) { b0 += ph[40 + k] * am[k]; b1 += ph[41 + k] * am[k + 1]; }
                float ev = a0 + a1, ov = b0 + b1;
                int s = s0 + j;
                if (s < 3)     ev += Mar[o * 192 + d * 3 + s];
                if (s + 1 < 3) ov += Mar[o * 192 + d * 3 + s + 1];
                wg[(size_t)s * 4096 + q]       = f2bf(ev);
                wg[(size_t)(s + 1) * 4096 + q] = f2bf(ov);
            }
            __syncthreads();
            if (tid == 0) {
                __threadfence();
                __hip_atomic_fetch_add(&jdone[Jg], 1, __ATOMIC_RELEASE, __HIP_MEMORY_SCOPE_AGENT);
            }
        } else {                                         // ---- spectral (R7) ----
            if (!seen_p0) {
                if (tid == 0)
                    while (__hip_atomic_load(p0done, __ATOMIC_ACQUIRE, __HIP_MEMORY_SCOPE_AGENT) < 384)
                        __builtin_amdgcn_s_sleep(2);
                __syncthreads();
                seen_p0 = true;
            }
            const int su = U - U_SP;
            // taper: su<992 full 64-s; else 32-s half of unit 992+(su-992)/2
            int mu = su, shalf = 0, slen = 64;
            if (su >= 992) { mu = 992 + ((su - 992) >> 1); shalf = (su - 992) & 1; slen = 32; }
            int g = 0;
            #pragma unroll 1
            while (g < 31 && (g + 1) * (64 - g) <= mu) ++g;
            const int rem = mu - g * (65 - g);
            const int cnt = 32 - g;
            const int col = (rem >= cnt) ? 1 : 0;
            const int J = 2 * g + col;
            const int I = g + (col ? rem - cnt : rem);
            const int t0 = I << 7, s0 = (J << 6) + (shalf << 5);
            const int nrows = 127 + slen;
            const int jmax = slen >> 1;
            const int base = 4096 + t0 - s0 - (slen - 1);

            // wait until W for this J is fully built (build is J-major: rare spin)
            if (tid == 0)
                while (__hip_atomic_load(&jdone[J], __ATOMIC_ACQUIRE, __HIP_MEMORY_SCOPE_AGENT) < 16)
                    __builtin_amdgcn_s_sleep(2);
            __syncthreads();

            // prefetch W pair (s0, s0+1)
            const u16* wbase = wg + (size_t)s0 * 4096;
            bf16x8 pre[4];
            pre[0] = *(const bf16x8*)(wbase + f0 * 8);
            pre[1] = *(const bf16x8*)(wbase + f1 * 8);
            pre[2] = *(const bf16x8*)(wbase + 4096 + f0 * 8);
            pre[3] = *(const bf16x8*)(wbase + 4096 + f1 * 8);

            // stage x window: nrows rows/batch
            #pragma unroll
            for (int b = 0; b < 2; ++b) {
                #pragma unroll 1
                for (int f = tid; f < nrows * 8; f += 256) {
                    int r = f >> 3, c = f & 7;
                    bf16x8 v = *(const bf16x8*)(xpad + (size_t)((b << 13) + base + r) * 64 + c * 8);
                    *(bf16x8*)(xs + ((b * 191 + r) * 8 + (c ^ (r & 7))) * 8) = v;
                }
            }

            f32x4 acc[8][4];
            #pragma unroll
            for (int mt = 0; mt < 8; ++mt)
                #pragma unroll
                for (int nt = 0; nt < 4; ++nt)
                    acc[mt][nt] = (f32x4){0.f, 0.f, 0.f, 0.f};

            const u16* xb = xs + batch * (191 * 64);
            const u16* wpar = wsm + par * 4096;

            #pragma unroll 1
            for (int j = 0; j < jmax; ++j) {
                __syncthreads();                         // prev W reads complete
                *(bf16x8*)(wsm + l0)        = pre[0];
                *(bf16x8*)(wsm + l1)        = pre[1];
                *(bf16x8*)(wsm + 4096 + l0) = pre[2];
                *(bf16x8*)(wsm + 4096 + l1) = pre[3];
                __syncthreads();                         // W pair visible
                if (j < jmax - 1) {
                    const u16* wp = wbase + (size_t)(2 * j + 2) * 4096;
                    pre[0] = *(const bf16x8*)(wp + f0 * 8);
                    pre[1] = *(const bf16x8*)(wp + f1 * 8);
                    pre[2] = *(const bf16x8*)(wp + 4096 + f0 * 8);
                    pre[3] = *(const bf16x8*)(wp + 4096 + f1 * 8);
                }
                const int ds = 2 * j + par;
                #pragma unroll
                for (int ks = 0; ks < 2; ++ks) {
                    const int kq = ks * 4 + q4;
                    bf16x8 bfv[4];
                    #pragma unroll
                    for (int nt = 0; nt < 4; ++nt) {
                        int o = nt * 16 + m15;
                        bfv[nt] = *(const bf16x8*)(wpar + (o * 8 + (kq ^ (o & 7))) * 8);
                    }
                    #pragma unroll
                    for (int mt = 0; mt < 8; ++mt) {
                        int r = mt * 16 + m15 + (slen - 1) - ds;
                        bf16x8 av = *(const bf16x8*)(xb + (r * 8 + (kq ^ (r & 7))) * 8);
                        #pragma unroll
                        for (int nt = 0; nt < 4; ++nt)
                            acc[mt][nt] = __builtin_amdgcn_mfma_f32_16x16x32_bf16(
                                av, bfv[nt], acc[mt][nt], 0, 0, 0);
                    }
                }
            }

            // merge parity-1 partials into parity-0 via LDS (wsm dead)
            float* fs = (float*)wsm;
            #pragma unroll
            for (int rd = 0; rd < 4; ++rd) {
                __syncthreads();
                if (par == 1) {
                    #pragma unroll
                    for (int i = 0; i < 8; ++i) {
                        int ti = rd * 8 + i;
                        *(f32x4*)(fs + (batch * 8 + i) * 256 + lane * 4) = acc[ti >> 2][ti & 3];
                    }
                }
                __syncthreads();
                if (par == 0) {
                    #pragma unroll
                    for (int i = 0; i < 8; ++i) {
                        int ti = rd * 8 + i;
                        f32x4 v = *(const f32x4*)(fs + (batch * 8 + i) * 256 + lane * 4);
                        acc[ti >> 2][ti & 3] += v;
                    }
                }
            }

            // epilogue (parity-0 waves): coalesced fp32 atomics
            if (par == 0) {
                #pragma unroll
                for (int mt = 0; mt < 8; ++mt) {
                    int t = t0 + mt * 16 + q4 * 4;
                    #pragma unroll
                    for (int nt = 0; nt < 4; ++nt) {
                        int o = nt * 16 + m15;
                        float* op = out + (size_t)((batch << 12) + t) * 64 + o;
                        #pragma unroll
                        for (int r = 0; r < 4; ++r)
                            atomicAdd(op + r * 64, acc[mt][nt][r]);
                    }
                }
            }
        }
    }
}

// ---------------------------------------------------------------------------
extern "C" void kernel_launch(void* const* d_in, const int* in_sizes, int n_in,
                              void* d_out, int out_size, void* d_ws, size_t ws_size,
                              hipStream_t stream) {
    const float* x   = (const float*)d_in[0];   // (2, 4096, 64)
    const float* phi = (const float*)d_in[1];   // (4096, 40)
    const float* M   = (const float*)d_in[2];   // (64, 64, 3)
    const float* Mp  = (const float*)d_in[3];   // (40, 64, 64)
    const float* Mm  = (const float*)d_in[4];   // (40, 64, 64)
    float* out = (float*)d_out;                 // (2, 4096, 64)

    // ws: [0,4096) ctrl (counters+flags) | xpad 2 MiB | wg 32 MiB | ApT/AmT
    int* ctrl = (int*)d_ws;
    u16* xpad = (u16*)((char*)d_ws + 4096);
    u16* wg   = (u16*)((char*)d_ws + 4096 + 2097152);
    float* ApT = (float*)((char*)d_ws + 4096 + 2097152 + 33554432);
    float* AmT = ApT + 40 * 4096;

    hipMemsetAsync(d_ws, 0, 4096, stream);
    k_fused<<<512, 256, 0, stream>>>(x, phi, M, Mp, Mm, xpad, wg, ApT, AmT, out, ctrl);
}

// Round 11
// 221.641 us; speedup vs baseline: 1.5843x; 1.5843x over previous
//
#include <hip/hip_runtime.h>

typedef short bf16x8 __attribute__((ext_vector_type(8)));
typedef float f32x4 __attribute__((ext_vector_type(4)));
typedef unsigned short u16;

__device__ __forceinline__ u16 f2bf(float f) {
    unsigned u = __builtin_bit_cast(unsigned, f);
    return (u16)((u + 0x7fffu + ((u >> 16) & 1u)) >> 16);   // RNE
}

// ---------------- kernel 1: transpose + zero out + counter -------------------
// blocks [0,40):   ApT/AmT[k][o][d] = (Mp +/- Mm)[k][d][o]
// blocks [40,168): zero d_out (2 MiB); block 40 zeros the task counter
__global__ __launch_bounds__(256)
void k_pre(const float* __restrict__ Mp, const float* __restrict__ Mm,
           float* __restrict__ ApT, float* __restrict__ AmT,
           float* __restrict__ out, int* __restrict__ counter) {
    __shared__ float tp[64 * 65], tm[64 * 65];
    if (blockIdx.x < 40) {
        const int k = blockIdx.x, tid = threadIdx.x;
        for (int f = tid; f < 4096; f += 256) {          // f = d*64 + o
            int d = f >> 6, o = f & 63;
            float p = Mp[k * 4096 + f], m = Mm[k * 4096 + f];
            tp[o * 65 + d] = p + m;
            tm[o * 65 + d] = p - m;
        }
        __syncthreads();
        for (int f = tid; f < 4096; f += 256) {          // f = o*64 + d
            int o = f >> 6, d = f & 63;
            ApT[k * 4096 + f] = tp[o * 65 + d];
            AmT[k * 4096 + f] = tm[o * 65 + d];
        }
    } else {
        const int bz = blockIdx.x - 40;                  // 128 blocks x 4096 floats
        if (bz == 0 && threadIdx.x == 0) *counter = 0;
        float* po = out + bz * 4096;
        #pragma unroll
        for (int i = 0; i < 4; ++i)
            *(f32x4*)(po + (threadIdx.x + i * 256) * 4) = (f32x4){0.f, 0.f, 0.f, 0.f};
    }
}

// ---------------- kernel 2: xpad  ||  build W --------------------------------
// blocks [0,256):    xpad[b][r][d] bf16 (r<4096 zeros, 4096+t = x[b,t,:])
// blocks [256,2304): build Wtot[s][o][d]: one s-PARITY per block (32 s each)
//   -> 40 regs/thread (not 80), VGPR ~70, ~7 waves/SIMD for s_load latency hiding
__global__ __launch_bounds__(256)
void k_mid(const float* __restrict__ x, u16* __restrict__ xpad,
           const float* __restrict__ phi, const float* __restrict__ ApT,
           const float* __restrict__ AmT, const float* __restrict__ Mar,
           u16* __restrict__ wg) {
    if (blockIdx.x < 256) {
        const int u = blockIdx.x;
        #pragma unroll
        for (int i = 0; i < 4; ++i) {
            int gid = (u * 4 + i) * 256 + threadIdx.x;
            int b = gid >> 17, rem = gid & 131071;
            int r = rem >> 4, c4 = rem & 15;
            u16 o0 = 0, o1 = 0, o2 = 0, o3 = 0;
            if (r >= 4096) {
                const f32x4 v = *(const f32x4*)(x + ((b << 12) + (r - 4096)) * 64 + c4 * 4);
                o0 = f2bf(v.x); o1 = f2bf(v.y); o2 = f2bf(v.z); o3 = f2bf(v.w);
            }
            u16* p = xpad + ((b << 13) + r) * 64 + c4 * 4;
            p[0] = o0; p[1] = o1; p[2] = o2; p[3] = o3;
        }
    } else {
        const int bi  = blockIdx.x - 256;
        const int par = bi & 1;                          // s parity
        const int sbq = bi >> 1;
        const int sb  = sbq >> 4, qb = sbq & 15;
        const int q   = qb * 256 + threadIdx.x;
        const int o   = q >> 6, d = q & 63;
        const float* A = (par ? AmT : ApT);

        float a[40];
        #pragma unroll
        for (int k = 0; k < 40; ++k) a[k] = A[k * 4096 + q];   // coalesced

        #pragma unroll 2
        for (int m = 0; m < 32; ++m) {
            const int s = sb * 64 + 2 * m + par;
            const float* ph = phi + s * 40;              // wave-uniform -> s_load
            float e0 = 0.f, e1 = 0.f;
            #pragma unroll
            for (int k = 0; k < 40; k += 2) { e0 += ph[k] * a[k]; e1 += ph[k + 1] * a[k + 1]; }
            float ev = e0 + e1;
            if (s < 3) ev += Mar[o * 192 + d * 3 + s];   // fold AR term
            wg[(size_t)s * 4096 + q] = f2bf(ev);
        }
    }
}

// ---------------- kernel 3: triangular conv-GEMM (R7-verbatim) ---------------
// s-parity waves, mt=8 x nt=4, 16x16x32 MFMA, 0-conflict swizzle, J-major
// dynamic order + 32-s tail taper. Best measured: 143 us, MfmaUtil 41%.
__global__ __launch_bounds__(256, 2)
void k_spectral(const u16* __restrict__ xpad, const u16* __restrict__ wg,
                float* __restrict__ out, int* __restrict__ counter) {
    __shared__ __align__(16) u16 xs[2 * 191 * 64];       // 47.75 KB x window
    __shared__ __align__(16) u16 wsm[2 * 64 * 64];       // 16 KB: [parity][o][chunk]
    __shared__ int sh;

    const int tid  = threadIdx.x;
    const int lane = tid & 63, w = tid >> 6;
    const int m15  = lane & 15, q4 = lane >> 4;
    const int par  = w >> 1, batch = w & 1;              // wave = (parity, batch)
    const int f0 = tid * 2, f1 = tid * 2 + 1;            // W staging granules
    const int l0 = (((f0 >> 3) * 8) + ((f0 & 7) ^ ((f0 >> 3) & 7))) * 8;
    const int l1 = (((f1 >> 3) * 8) + ((f1 & 7) ^ ((f1 >> 3) & 7))) * 8;

    for (;;) {
        __syncthreads();                                 // xs/wsm/sh reuse guard
        if (tid == 0) sh = atomicAdd(counter, 1);
        __syncthreads();
        const int U = sh;
        if (U >= 1120) break;

        // taper: U<992 -> full unit; else half task (32-s) of unit 992+(U-992)/2
        int mu = U, shalf = 0, slen = 64;
        if (U >= 992) { mu = 992 + ((U - 992) >> 1); shalf = (U - 992) & 1; slen = 32; }
        // J-major unit decode: group g=J>>1, G(g)=g(65-g), column cnt=32-g
        int g = 0;
        #pragma unroll 1
        while (g < 31 && (g + 1) * (64 - g) <= mu) ++g;
        const int rem = mu - g * (65 - g);
        const int cnt = 32 - g;
        const int col = (rem >= cnt) ? 1 : 0;
        const int J = 2 * g + col;
        const int I = g + (col ? rem - cnt : rem);
        const int t0 = I << 7, s0 = (J << 6) + (shalf << 5);
        const int nrows = 127 + slen;
        const int jmax = slen >> 1;
        const int base = 4096 + t0 - s0 - (slen - 1);    // window start row in xpad

        // prefetch W pair (s0, s0+1)
        const u16* wbase = wg + (size_t)s0 * 4096;
        bf16x8 pre[4];
        pre[0] = *(const bf16x8*)(wbase + f0 * 8);
        pre[1] = *(const bf16x8*)(wbase + f1 * 8);
        pre[2] = *(const bf16x8*)(wbase + 4096 + f0 * 8);
        pre[3] = *(const bf16x8*)(wbase + 4096 + f1 * 8);

        // ---- stage x window: nrows rows/batch ----
        #pragma unroll
        for (int b = 0; b < 2; ++b) {
            #pragma unroll 1
            for (int f = tid; f < nrows * 8; f += 256) {
                int r = f >> 3, c = f & 7;
                bf16x8 v = *(const bf16x8*)(xpad + (size_t)((b << 13) + base + r) * 64 + c * 8);
                *(bf16x8*)(xs + ((b * 191 + r) * 8 + (c ^ (r & 7))) * 8) = v;
            }
        }

        f32x4 acc[8][4];
        #pragma unroll
        for (int mt = 0; mt < 8; ++mt)
            #pragma unroll
            for (int nt = 0; nt < 4; ++nt)
                acc[mt][nt] = (f32x4){0.f, 0.f, 0.f, 0.f};

        const u16* xb = xs + batch * (191 * 64);

        #pragma unroll 1
        for (int j = 0; j < jmax; ++j) {
            __syncthreads();                             // prev W reads complete
            *(bf16x8*)(wsm + l0)        = pre[0];
            *(bf16x8*)(wsm + l1)        = pre[1];
            *(bf16x8*)(wsm + 4096 + l0) = pre[2];
            *(bf16x8*)(wsm + 4096 + l1) = pre[3];
            __syncthreads();                             // W pair visible
            if (j < jmax - 1) {                          // prefetch next pair
                const u16* wp = wbase + (size_t)(2 * j + 2) * 4096;
                pre[0] = *(const bf16x8*)(wp + f0 * 8);
                pre[1] = *(const bf16x8*)(wp + f1 * 8);
                pre[2] = *(const bf16x8*)(wp + 4096 + f0 * 8);
                pre[3] = *(const bf16x8*)(wp + 4096 + f1 * 8);
            }
            const u16* wpar = wsm + par * 4096;
            const int ds = 2 * j + par;                  // this wave's s offset
            #pragma unroll
            for (int ks = 0; ks < 2; ++ks) {
                const int kq = ks * 4 + q4;
                bf16x8 bf[4];
                #pragma unroll
                for (int nt = 0; nt < 4; ++nt) {
                    int o = nt * 16 + m15;
                    bf[nt] = *(const bf16x8*)(wpar + (o * 8 + (kq ^ (o & 7))) * 8);
                }
                #pragma unroll
                for (int mt = 0; mt < 8; ++mt) {
                    int r = mt * 16 + m15 + (slen - 1) - ds;   // in [0, nrows-1]
                    bf16x8 av = *(const bf16x8*)(xb + (r * 8 + (kq ^ (r & 7))) * 8);
                    #pragma unroll
                    for (int nt = 0; nt < 4; ++nt)
                        acc[mt][nt] = __builtin_amdgcn_mfma_f32_16x16x32_bf16(
                            av, bf[nt], acc[mt][nt], 0, 0, 0);
                }
            }
        }

        // ---- merge parity-1 partials into parity-0 accs via LDS (wsm dead) ----
        float* fs = (float*)wsm;                         // 4096 floats (16 KB)
        #pragma unroll
        for (int rd = 0; rd < 4; ++rd) {
            __syncthreads();
            if (par == 1) {
                #pragma unroll
                for (int i = 0; i < 8; ++i) {
                    int ti = rd * 8 + i;
                    *(f32x4*)(fs + (batch * 8 + i) * 256 + lane * 4) = acc[ti >> 2][ti & 3];
                }
            }
            __syncthreads();
            if (par == 0) {
                #pragma unroll
                for (int i = 0; i < 8; ++i) {
                    int ti = rd * 8 + i;
                    f32x4 v = *(const f32x4*)(fs + (batch * 8 + i) * 256 + lane * 4);
                    acc[ti >> 2][ti & 3] += v;
                }
            }
        }

        // ---- epilogue (parity-0 waves only): coalesced fp32 atomics ----
        if (par == 0) {
            #pragma unroll
            for (int mt = 0; mt < 8; ++mt) {
                int t = t0 + mt * 16 + q4 * 4;
                #pragma unroll
                for (int nt = 0; nt < 4; ++nt) {
                    int o = nt * 16 + m15;
                    float* op = out + (size_t)((batch << 12) + t) * 64 + o;
                    #pragma unroll
                    for (int r = 0; r < 4; ++r)
                        atomicAdd(op + r * 64, acc[mt][nt][r]);
                }
            }
        }
    }
}

// ---------------------------------------------------------------------------
extern "C" void kernel_launch(void* const* d_in, const int* in_sizes, int n_in,
                              void* d_out, int out_size, void* d_ws, size_t ws_size,
                              hipStream_t stream) {
    const float* x   = (const float*)d_in[0];   // (2, 4096, 64)
    const float* phi = (const float*)d_in[1];   // (4096, 40)
    const float* M   = (const float*)d_in[2];   // (64, 64, 3)
    const float* Mp  = (const float*)d_in[3];   // (40, 64, 64)
    const float* Mm  = (const float*)d_in[4];   // (40, 64, 64)
    float* out = (float*)d_out;                 // (2, 4096, 64)

    // ws: [0,4096) counter | xpad 2 MiB | wg 32 MiB | ApT/AmT 2x640 KiB
    int* counter = (int*)d_ws;
    u16* xpad = (u16*)((char*)d_ws + 4096);
    u16* wg   = (u16*)((char*)d_ws + 4096 + 2097152);
    float* ApT = (float*)((char*)d_ws + 4096 + 2097152 + 33554432);
    float* AmT = ApT + 40 * 4096;

    k_pre<<<168, 256, 0, stream>>>(Mp, Mm, ApT, AmT, out, counter);
    k_mid<<<2304, 256, 0, stream>>>(x, xpad, phi, ApT, AmT, M, wg);
    k_spectral<<<512, 256, 0, stream>>>(xpad, wg, out, counter);
}